// Round 1
// baseline (3438.882 us; speedup 1.0000x reference)
//
#include <hip/hip_runtime.h>
#include <hip/hip_bf16.h>

// Problem constants (from reference)
#define NN 100000   // nodes
#define FF 10       // input features
#define HH 20       // hidden dim
#define GG 512      // graphs
#define LL 2        // labels

// ---------------------------------------------------------------------------
// Edge scatter: agg[dst] += x[src], parallelized as (edge, vec-chunk).
// D = feature dim, VEC = floats per chunk, D == 5*VEC (10=5*2, 20=5*4).
// Row stride D*4 bytes is a multiple of VEC*4 (80B = 5*16B, 40B = 5*8B), so
// vector loads stay aligned.
// ---------------------------------------------------------------------------
template<int D, int VEC>
__global__ __launch_bounds__(256) void scatter_add_kernel(
    const float* __restrict__ x, const int* __restrict__ src,
    const int* __restrict__ dst, float* __restrict__ agg, int E) {
  int idx = blockIdx.x * 256 + threadIdx.x;
  int total = E * 5;
  if (idx >= total) return;
  int e = idx / 5;           // compiler magic-mul
  int c = idx - e * 5;
  int s = src[e];
  int t = dst[e];
  const float* xs = x + (long long)s * D + c * VEC;
  float* ag = agg + (long long)t * D + c * VEC;
  if (VEC == 4) {
    float4 v = *(const float4*)xs;
    atomicAdd(ag + 0, v.x);
    atomicAdd(ag + 1, v.y);
    atomicAdd(ag + 2, v.z);
    atomicAdd(ag + 3, v.w);
  } else {
    float2 v = *(const float2*)xs;
    atomicAdd(ag + 0, v.x);
    atomicAdd(ag + 1, v.y);
  }
}

// ---------------------------------------------------------------------------
// Fused dense: out[n,j] = relu(sum_f agg[n,f]*Wrel[f,j] + b[j]
//                              + sum_f  xin[n,f]*Wroot[f,j])
// Thread per (node, out-feature). Weights in LDS.
// ---------------------------------------------------------------------------
template<int DIN>
__global__ __launch_bounds__(256) void gemm_root_relu_kernel(
    const float* __restrict__ agg, const float* __restrict__ xin,
    const float* __restrict__ Wrel, const float* __restrict__ b,
    const float* __restrict__ Wroot, float* __restrict__ out, int n_nodes) {
  __shared__ float sWrel[DIN * HH];
  __shared__ float sWroot[DIN * HH];
  __shared__ float sb[HH];
  for (int i = threadIdx.x; i < DIN * HH; i += 256) {
    sWrel[i] = Wrel[i];
    sWroot[i] = Wroot[i];
  }
  if (threadIdx.x < HH) sb[threadIdx.x] = b[threadIdx.x];
  __syncthreads();
  int idx = blockIdx.x * 256 + threadIdx.x;
  if (idx >= n_nodes * HH) return;
  int n = idx / HH;
  int j = idx - n * HH;
  const float* ar = agg + (long long)n * DIN;
  const float* xr = xin + (long long)n * DIN;
  float acc = sb[j];
#pragma unroll
  for (int f = 0; f < DIN; f++) {
    acc += ar[f] * sWrel[f * HH + j];
    acc += xr[f] * sWroot[f * HH + j];
  }
  out[idx] = fmaxf(acc, 0.0f);
}

// ---------------------------------------------------------------------------
// Pool: segment sum + segment max (+ counts) over sorted batch ids.
// Values are post-ReLU (>= 0) so int-compare atomicMax on float bits is
// order-correct, and memset-0 init reproduces where(count>0, max, 0).
// ---------------------------------------------------------------------------
__global__ __launch_bounds__(256) void pool_kernel(
    const float* __restrict__ h, const int* __restrict__ batch,
    float* __restrict__ sump, int* __restrict__ maxp, float* __restrict__ cnt,
    int n_nodes) {
  int idx = blockIdx.x * 256 + threadIdx.x;
  if (idx >= n_nodes * HH) return;
  int n = idx / HH;
  int j = idx - n * HH;
  int g = batch[n];
  float v = h[idx];
  atomicAdd(&sump[g * HH + j], v);
  atomicMax(&maxp[g * HH + j], __float_as_int(v));
  if (j == 0) atomicAdd(&cnt[g], 1.0f);
}

// ---------------------------------------------------------------------------
// Readout: out[g,l] = b[l] + sum_j max[g,j]*W[j,l] + mean[g,j]*W[HH+j,l]
// ---------------------------------------------------------------------------
__global__ __launch_bounds__(256) void readout_kernel(
    const float* __restrict__ sump, const int* __restrict__ maxp,
    const float* __restrict__ cnt, const float* __restrict__ Wlin,
    const float* __restrict__ blin, float* __restrict__ out) {
  int idx = blockIdx.x * 256 + threadIdx.x;
  if (idx >= GG * LL) return;
  int g = idx / LL;
  int l = idx - g * LL;
  float c = cnt[g];
  float inv = 1.0f / fmaxf(c, 1.0f);
  float acc = blin[l];
#pragma unroll
  for (int j = 0; j < HH; j++) {
    float mx = __int_as_float(maxp[g * HH + j]);
    float mean = sump[g * HH + j] * inv;
    acc += mx * Wlin[j * LL + l];
    acc += mean * Wlin[(HH + j) * LL + l];
  }
  out[idx] = acc;
}

extern "C" void kernel_launch(void* const* d_in, const int* in_sizes, int n_in,
                              void* d_out, int out_size, void* d_ws,
                              size_t ws_size, hipStream_t stream) {
  const float* x = (const float*)d_in[0];
  const int* edge_index = (const int*)d_in[1];
  const int* batch = (const int*)d_in[2];
  const float* W_rel1 = (const float*)d_in[3];
  const float* b1 = (const float*)d_in[4];
  const float* W_root1 = (const float*)d_in[5];
  const float* W_rel2 = (const float*)d_in[6];
  const float* b2 = (const float*)d_in[7];
  const float* W_root2 = (const float*)d_in[8];
  const float* W_rel3 = (const float*)d_in[9];
  const float* b3 = (const float*)d_in[10];
  const float* W_root3 = (const float*)d_in[11];
  const float* W_lin = (const float*)d_in[12];
  const float* b_lin = (const float*)d_in[13];
  float* out = (float*)d_out;

  const int E = in_sizes[1] / 2;
  const int n_nodes = in_sizes[0] / FF;  // == NN
  const int* src = edge_index;
  const int* dst = edge_index + E;

  // Workspace layout (floats)
  float* agg = (float*)d_ws;                       // NN*HH (layer1 uses NN*FF)
  float* bufA = agg + (size_t)NN * HH;             // NN*HH
  float* bufB = bufA + (size_t)NN * HH;            // NN*HH
  float* sump = bufB + (size_t)NN * HH;            // GG*HH
  int* maxp = (int*)(sump + GG * HH);              // GG*HH
  float* cnt = (float*)(maxp + GG * HH);           // GG

  const int nodeF_threads = n_nodes * HH;
  const int nodeF_blocks = (nodeF_threads + 255) / 256;
  const int edge_threads = E * 5;
  const int edge_blocks = (edge_threads + 255) / 256;

  // ---- Layer 1: F(10) -> H(20) ----
  hipMemsetAsync(agg, 0, (size_t)n_nodes * FF * sizeof(float), stream);
  scatter_add_kernel<FF, 2><<<edge_blocks, 256, 0, stream>>>(x, src, dst, agg, E);
  gemm_root_relu_kernel<FF><<<nodeF_blocks, 256, 0, stream>>>(
      agg, x, W_rel1, b1, W_root1, bufA, n_nodes);

  // ---- Layer 2: H -> H ----
  hipMemsetAsync(agg, 0, (size_t)n_nodes * HH * sizeof(float), stream);
  scatter_add_kernel<HH, 4><<<edge_blocks, 256, 0, stream>>>(bufA, src, dst, agg, E);
  gemm_root_relu_kernel<HH><<<nodeF_blocks, 256, 0, stream>>>(
      agg, bufA, W_rel2, b2, W_root2, bufB, n_nodes);

  // ---- Layer 3: H -> H ----
  hipMemsetAsync(agg, 0, (size_t)n_nodes * HH * sizeof(float), stream);
  scatter_add_kernel<HH, 4><<<edge_blocks, 256, 0, stream>>>(bufB, src, dst, agg, E);
  gemm_root_relu_kernel<HH><<<nodeF_blocks, 256, 0, stream>>>(
      agg, bufB, W_rel3, b3, W_root3, bufA, n_nodes);

  // ---- Pooling ----
  hipMemsetAsync(sump, 0, (size_t)GG * HH * sizeof(float), stream);
  hipMemsetAsync(maxp, 0, (size_t)GG * HH * sizeof(int), stream);
  hipMemsetAsync(cnt, 0, (size_t)GG * sizeof(float), stream);
  pool_kernel<<<nodeF_blocks, 256, 0, stream>>>(bufA, batch, sump, maxp, cnt,
                                                n_nodes);

  // ---- Readout ----
  readout_kernel<<<(GG * LL + 255) / 256, 256, 0, stream>>>(
      sump, maxp, cnt, W_lin, b_lin, out);
}

// Round 2
// 1136.184 us; speedup vs baseline: 3.0267x; 3.0267x over previous
//
#include <hip/hip_runtime.h>
#include <hip/hip_bf16.h>

#define NN 100000   // nodes
#define FF 10       // input features
#define HH 20       // hidden dim
#define GG 512      // graphs
#define LL 2        // labels

// ---------------------------------------------------------------------------
// CSR build step 1: histogram of dst
// ---------------------------------------------------------------------------
__global__ __launch_bounds__(256) void hist_kernel(
    const int* __restrict__ dst, int* __restrict__ deg, int E) {
  int e = blockIdx.x * 256 + threadIdx.x;
  if (e >= E) return;
  atomicAdd(&deg[dst[e]], 1);
}

// ---------------------------------------------------------------------------
// CSR build step 2: single-block exclusive scan of deg -> rofs, cur
// 1024 threads, each handles ceil(n/1024) sequential elements.
// ---------------------------------------------------------------------------
__global__ __launch_bounds__(1024) void scan_kernel(
    const int* __restrict__ deg, int* __restrict__ rofs,
    int* __restrict__ cur, int n) {
  __shared__ int partial[1024];
  int t = threadIdx.x;
  int per = (n + 1023) / 1024;
  int start = t * per;
  int end = min(start + per, n);
  int s = 0;
  for (int i = start; i < end; i++) s += deg[i];
  partial[t] = s;
  __syncthreads();
  // Hillis-Steele inclusive scan in LDS
  for (int off = 1; off < 1024; off <<= 1) {
    int tmp = (t >= off) ? partial[t - off] : 0;
    __syncthreads();
    partial[t] += tmp;
    __syncthreads();
  }
  int run = partial[t] - s;  // exclusive prefix
  for (int i = start; i < end; i++) {
    rofs[i] = run;
    cur[i] = run;
    run += deg[i];
  }
}

// ---------------------------------------------------------------------------
// CSR build step 3: place src into dst-sorted order.
// After this kernel, cur[n] == row_end(n) == rofs[n] + deg[n].
// ---------------------------------------------------------------------------
__global__ __launch_bounds__(256) void place_kernel(
    const int* __restrict__ src, const int* __restrict__ dst,
    int* __restrict__ cur, int* __restrict__ srt, int E) {
  int e = blockIdx.x * 256 + threadIdx.x;
  if (e >= E) return;
  int d = dst[e];
  int pos = atomicAdd(&cur[d], 1);
  srt[pos] = src[e];
}

// ---------------------------------------------------------------------------
// Fused layer: per node n,
//   agg = sum_{k in row(n)} xin[srt[k]]               (register accumulate)
//   out[n,:] = relu(agg @ Wrel + b + xin[n,:] @ Wroot)
// Thread per node; weights broadcast from LDS.
// DIN=20: rows are 80B (16B aligned) -> float4 loads.
// DIN=10: rows are 40B (8B aligned)  -> float2 loads.
// ---------------------------------------------------------------------------
template<int DIN>
__global__ __launch_bounds__(256) void layer_kernel(
    const float* __restrict__ xin, const int* __restrict__ rofs,
    const int* __restrict__ rend, const int* __restrict__ srt,
    const float* __restrict__ Wrel, const float* __restrict__ b,
    const float* __restrict__ Wroot, float* __restrict__ out, int n_nodes) {
  __shared__ float sWrel[DIN * HH];
  __shared__ float sWroot[DIN * HH];
  __shared__ float sb[HH];
  for (int i = threadIdx.x; i < DIN * HH; i += 256) {
    sWrel[i] = Wrel[i];
    sWroot[i] = Wroot[i];
  }
  if (threadIdx.x < HH) sb[threadIdx.x] = b[threadIdx.x];
  __syncthreads();
  int n = blockIdx.x * 256 + threadIdx.x;
  if (n >= n_nodes) return;

  float acc[DIN];
#pragma unroll
  for (int f = 0; f < DIN; f++) acc[f] = 0.0f;

  int k0 = rofs[n];
  int k1 = rend[n];
  for (int k = k0; k < k1; k++) {
    int s = srt[k];
    const float* xs = xin + (size_t)s * DIN;
    if (DIN == 20) {
#pragma unroll
      for (int c = 0; c < 5; c++) {
        float4 v = *(const float4*)(xs + 4 * c);
        acc[4 * c + 0] += v.x;
        acc[4 * c + 1] += v.y;
        acc[4 * c + 2] += v.z;
        acc[4 * c + 3] += v.w;
      }
    } else {
#pragma unroll
      for (int c = 0; c < 5; c++) {
        float2 v = *(const float2*)(xs + 2 * c);
        acc[2 * c + 0] += v.x;
        acc[2 * c + 1] += v.y;
      }
    }
  }

  // root row
  float xr[DIN];
  {
    const float* xn = xin + (size_t)n * DIN;
    if (DIN == 20) {
#pragma unroll
      for (int c = 0; c < 5; c++) {
        float4 v = *(const float4*)(xn + 4 * c);
        xr[4 * c + 0] = v.x;
        xr[4 * c + 1] = v.y;
        xr[4 * c + 2] = v.z;
        xr[4 * c + 3] = v.w;
      }
    } else {
#pragma unroll
      for (int c = 0; c < 5; c++) {
        float2 v = *(const float2*)(xn + 2 * c);
        xr[2 * c + 0] = v.x;
        xr[2 * c + 1] = v.y;
      }
    }
  }

  float o[HH];
#pragma unroll
  for (int j = 0; j < HH; j++) o[j] = sb[j];
#pragma unroll
  for (int f = 0; f < DIN; f++) {
    float a = acc[f];
    float xv = xr[f];
#pragma unroll
    for (int j = 0; j < HH; j++) {
      o[j] += a * sWrel[f * HH + j] + xv * sWroot[f * HH + j];
    }
  }
  float* orow = out + (size_t)n * HH;
#pragma unroll
  for (int c = 0; c < 5; c++) {
    float4 v;
    v.x = fmaxf(o[4 * c + 0], 0.0f);
    v.y = fmaxf(o[4 * c + 1], 0.0f);
    v.z = fmaxf(o[4 * c + 2], 0.0f);
    v.w = fmaxf(o[4 * c + 3], 0.0f);
    *(float4*)(orow + 4 * c) = v;
  }
}

// ---------------------------------------------------------------------------
// Pool: segment sum + max + counts. Post-ReLU values >= 0, so int atomicMax
// on float bits is order-correct and memset-0 init gives where(cnt>0,max,0).
// ---------------------------------------------------------------------------
__global__ __launch_bounds__(256) void pool_kernel(
    const float* __restrict__ h, const int* __restrict__ batch,
    float* __restrict__ sump, int* __restrict__ maxp, float* __restrict__ cnt,
    int n_nodes) {
  int idx = blockIdx.x * 256 + threadIdx.x;
  if (idx >= n_nodes * HH) return;
  int n = idx / HH;
  int j = idx - n * HH;
  int g = batch[n];
  float v = h[idx];
  atomicAdd(&sump[g * HH + j], v);
  atomicMax(&maxp[g * HH + j], __float_as_int(v));
  if (j == 0) atomicAdd(&cnt[g], 1.0f);
}

__global__ __launch_bounds__(256) void readout_kernel(
    const float* __restrict__ sump, const int* __restrict__ maxp,
    const float* __restrict__ cnt, const float* __restrict__ Wlin,
    const float* __restrict__ blin, float* __restrict__ out) {
  int idx = blockIdx.x * 256 + threadIdx.x;
  if (idx >= GG * LL) return;
  int g = idx / LL;
  int l = idx - g * LL;
  float c = cnt[g];
  float inv = 1.0f / fmaxf(c, 1.0f);
  float acc = blin[l];
#pragma unroll
  for (int j = 0; j < HH; j++) {
    float mx = __int_as_float(maxp[g * HH + j]);
    float mean = sump[g * HH + j] * inv;
    acc += mx * Wlin[j * LL + l];
    acc += mean * Wlin[(HH + j) * LL + l];
  }
  out[idx] = acc;
}

extern "C" void kernel_launch(void* const* d_in, const int* in_sizes, int n_in,
                              void* d_out, int out_size, void* d_ws,
                              size_t ws_size, hipStream_t stream) {
  const float* x = (const float*)d_in[0];
  const int* edge_index = (const int*)d_in[1];
  const int* batch = (const int*)d_in[2];
  const float* W_rel1 = (const float*)d_in[3];
  const float* b1 = (const float*)d_in[4];
  const float* W_root1 = (const float*)d_in[5];
  const float* W_rel2 = (const float*)d_in[6];
  const float* b2 = (const float*)d_in[7];
  const float* W_root2 = (const float*)d_in[8];
  const float* W_rel3 = (const float*)d_in[9];
  const float* b3 = (const float*)d_in[10];
  const float* W_root3 = (const float*)d_in[11];
  const float* W_lin = (const float*)d_in[12];
  const float* b_lin = (const float*)d_in[13];
  float* out = (float*)d_out;

  const int E = in_sizes[1] / 2;
  const int n_nodes = in_sizes[0] / FF;  // == NN
  const int* src = edge_index;
  const int* dst = edge_index + E;

  // Workspace layout
  int* deg = (int*)d_ws;                         // NN ints
  int* rofs = deg + NN;                          // NN ints
  int* cur = rofs + NN;                          // NN ints (== row_end after place)
  int* srt = cur + NN;                           // E ints
  float* bufA = (float*)(srt + E);               // NN*HH floats
  float* bufB = bufA + (size_t)NN * HH;          // NN*HH floats
  float* sump = bufB + (size_t)NN * HH;          // GG*HH
  int* maxp = (int*)(sump + GG * HH);            // GG*HH
  float* cnt = (float*)(maxp + GG * HH);         // GG
  // total ~= 1.2MB + 12.8MB + 16MB + 82KB ~= 30.1 MB

  const int edge_blocks = (E + 255) / 256;
  const int node_blocks = (n_nodes + 255) / 256;
  const int nodeF_blocks = (n_nodes * HH + 255) / 256;

  // ---- CSR build (per call; ws is re-poisoned every launch) ----
  hipMemsetAsync(deg, 0, (size_t)NN * sizeof(int), stream);
  hist_kernel<<<edge_blocks, 256, 0, stream>>>(dst, deg, E);
  scan_kernel<<<1, 1024, 0, stream>>>(deg, rofs, cur, n_nodes);
  place_kernel<<<edge_blocks, 256, 0, stream>>>(src, dst, cur, srt, E);

  // ---- Layers (gather + dense fused, atomic-free) ----
  layer_kernel<FF><<<node_blocks, 256, 0, stream>>>(
      x, rofs, cur, srt, W_rel1, b1, W_root1, bufA, n_nodes);
  layer_kernel<HH><<<node_blocks, 256, 0, stream>>>(
      bufA, rofs, cur, srt, W_rel2, b2, W_root2, bufB, n_nodes);
  layer_kernel<HH><<<node_blocks, 256, 0, stream>>>(
      bufB, rofs, cur, srt, W_rel3, b3, W_root3, bufA, n_nodes);

  // ---- Pooling ----
  hipMemsetAsync(sump, 0, (size_t)GG * HH * sizeof(float), stream);
  hipMemsetAsync(maxp, 0, (size_t)GG * HH * sizeof(int), stream);
  hipMemsetAsync(cnt, 0, (size_t)GG * sizeof(float), stream);
  pool_kernel<<<nodeF_blocks, 256, 0, stream>>>(bufA, batch, sump, maxp, cnt,
                                                n_nodes);

  // ---- Readout ----
  readout_kernel<<<(GG * LL + 255) / 256, 256, 0, stream>>>(
      sump, maxp, cnt, W_lin, b_lin, out);
}

// Round 3
// 494.490 us; speedup vs baseline: 6.9544x; 2.2977x over previous
//
#include <hip/hip_runtime.h>
#include <hip/hip_bf16.h>

#define NN 100000   // nodes
#define FF 10       // input features
#define HH 20       // hidden dim
#define GG 512      // graphs
#define LL 2        // labels

#define NB 200      // dst buckets
#define BNODES 500  // nodes per bucket (NN / NB)
#define TILE 4096   // edges per block in multisplit

// ---------------------------------------------------------------------------
// K0: per-bucket edge counts (LDS histogram, then merge).
// ---------------------------------------------------------------------------
__global__ __launch_bounds__(256) void bucket_count_kernel(
    const int* __restrict__ dst, int* __restrict__ bcnt, int E) {
  __shared__ int lh[NB];
  for (int i = threadIdx.x; i < NB; i += 256) lh[i] = 0;
  __syncthreads();
  int base = blockIdx.x * TILE;
  for (int i = threadIdx.x; i < TILE; i += 256) {
    int e = base + i;
    if (e < E) atomicAdd(&lh[dst[e] / BNODES], 1);
  }
  __syncthreads();
  for (int i = threadIdx.x; i < NB; i += 256) {
    int c = lh[i];
    if (c) atomicAdd(&bcnt[i], c);
  }
}

// ---------------------------------------------------------------------------
// K1: scan bucket counts -> gofs[NB+1], init cursor = bucket base.
// ---------------------------------------------------------------------------
__global__ __launch_bounds__(256) void bucket_scan_kernel(
    const int* __restrict__ bcnt, int* __restrict__ gofs,
    int* __restrict__ cursor) {
  __shared__ int sh[256];
  int t = threadIdx.x;
  int own = (t < NB) ? bcnt[t] : 0;
  sh[t] = own;
  __syncthreads();
  for (int off = 1; off < 256; off <<= 1) {
    int tmp = (t >= off) ? sh[t - off] : 0;
    __syncthreads();
    sh[t] += tmp;
    __syncthreads();
  }
  if (t < NB) {
    int ex = sh[t] - own;
    gofs[t] = ex;
    cursor[t] = ex;
  }
  if (t == NB) gofs[NB] = sh[NB - 1];
}

// ---------------------------------------------------------------------------
// K2: multisplit. Reorder a TILE of edges by bucket in LDS, then write each
// bucket run contiguously (coalesced, single-block line ownership).
// Payload pack: (local_dst<<18) | src   (local_dst<500 -> 9b, src<2^17 -> 18b)
// ---------------------------------------------------------------------------
__global__ __launch_bounds__(256) void multisplit_kernel(
    const int* __restrict__ src, const int* __restrict__ dst,
    int* __restrict__ cursor, unsigned int* __restrict__ pay, int E) {
  __shared__ unsigned int spay[TILE];
  __shared__ unsigned int sbkr[TILE];   // (bucket<<16) | rank
  __shared__ unsigned int sord[TILE];   // bucket-sorted payloads
  __shared__ unsigned char sdbk[TILE];  // bucket of each sorted slot
  __shared__ int lhist[NB];
  __shared__ int lofs[NB];
  __shared__ int gbase[NB];
  __shared__ int sscan[256];

  int t = threadIdx.x;
  for (int i = t; i < NB; i += 256) lhist[i] = 0;
  __syncthreads();

  int base = blockIdx.x * TILE;
  int count = E - base;
  if (count > TILE) count = TILE;

  for (int i = t; i < TILE; i += 256) {
    int e = base + i;
    if (e < E) {
      int d = dst[e];
      int s = src[e];
      int bk = d / BNODES;
      int ld = d - bk * BNODES;
      spay[i] = ((unsigned)ld << 18) | (unsigned)s;
      int r = atomicAdd(&lhist[bk], 1);
      sbkr[i] = ((unsigned)bk << 16) | (unsigned)r;
    } else {
      sbkr[i] = 0xFFFFFFFFu;
    }
  }
  __syncthreads();

  // exclusive scan of lhist (NB <= 256)
  int own = (t < NB) ? lhist[t] : 0;
  sscan[t] = own;
  __syncthreads();
  for (int off = 1; off < 256; off <<= 1) {
    int tmp = (t >= off) ? sscan[t - off] : 0;
    __syncthreads();
    sscan[t] += tmp;
    __syncthreads();
  }
  if (t < NB) {
    lofs[t] = sscan[t] - own;
    gbase[t] = own ? atomicAdd(&cursor[t], own) : 0;
  }
  __syncthreads();

  // scatter into bucket-sorted LDS order
  for (int i = t; i < TILE; i += 256) {
    unsigned int br = sbkr[i];
    if (br != 0xFFFFFFFFu) {
      int bk = br >> 16;
      int r = br & 0xFFFF;
      int slot = lofs[bk] + r;
      sord[slot] = spay[i];
      sdbk[slot] = (unsigned char)bk;
    }
  }
  __syncthreads();

  // coalesced run writes
  for (int i = t; i < count; i += 256) {
    int bk = sdbk[i];
    pay[gbase[bk] + (i - lofs[bk])] = sord[i];
  }
}

// ---------------------------------------------------------------------------
// K3: per-bucket CSR finalize. One block owns one 500-node bucket; all
// scattered writes confined to a single-block-owned region.
// ---------------------------------------------------------------------------
__global__ __launch_bounds__(256) void bucket_csr_kernel(
    const unsigned int* __restrict__ pay, const int* __restrict__ gofs,
    int* __restrict__ srt, int* __restrict__ rofs, int* __restrict__ rend) {
  __shared__ int lhist[BNODES];
  __shared__ int lofs[BNODES];
  __shared__ int lcur[BNODES];
  __shared__ int ss[512];
  int b = blockIdx.x;
  int t = threadIdx.x;
  int k0 = gofs[b], k1 = gofs[b + 1];

  for (int i = t; i < BNODES; i += 256) lhist[i] = 0;
  __syncthreads();
  for (int k = k0 + t; k < k1; k += 256)
    atomicAdd(&lhist[pay[k] >> 18], 1);
  __syncthreads();

  // exclusive scan of 500 (512-wide Hillis-Steele, 2 elems/thread)
  ss[t] = (t < BNODES) ? lhist[t] : 0;
  ss[t + 256] = (t + 256 < BNODES) ? lhist[t + 256] : 0;
  __syncthreads();
  for (int off = 1; off < 512; off <<= 1) {
    int a0 = (t >= off) ? ss[t - off] : 0;
    int a1 = (t + 256 >= off) ? ss[t + 256 - off] : 0;
    __syncthreads();
    ss[t] += a0;
    ss[t + 256] += a1;
    __syncthreads();
  }
  for (int i = t; i < BNODES; i += 256) {
    int ex = ss[i] - lhist[i];
    lofs[i] = ex;
    lcur[i] = 0;
    rofs[b * BNODES + i] = k0 + ex;
    rend[b * BNODES + i] = k0 + ex + lhist[i];
  }
  __syncthreads();

  for (int k = k0 + t; k < k1; k += 256) {
    unsigned int p = pay[k];
    int ld = p >> 18;
    int s = (int)(p & 0x3FFFFu);
    int r = atomicAdd(&lcur[ld], 1);
    srt[k0 + lofs[ld] + r] = s;
  }
}

// ---------------------------------------------------------------------------
// Gather: thread per (node, vec-chunk); 5 chunks cover a row.
// ---------------------------------------------------------------------------
template<int DIN, int VEC>
__global__ __launch_bounds__(256) void gather_kernel(
    const float* __restrict__ xin, const int* __restrict__ rofs,
    const int* __restrict__ rend, const int* __restrict__ srt,
    float* __restrict__ agg, int n_nodes) {
  int id = blockIdx.x * 256 + threadIdx.x;
  if (id >= n_nodes * 5) return;
  int n = id / 5;
  int c = id - n * 5;
  int k0 = rofs[n], k1 = rend[n];
  float a0 = 0, a1 = 0, a2 = 0, a3 = 0;
  const float* xb = xin + c * VEC;
  for (int k = k0; k < k1; k++) {
    int s = srt[k];
    const float* xs = xb + (size_t)s * DIN;
    if (VEC == 4) {
      float4 v = *(const float4*)xs;
      a0 += v.x; a1 += v.y; a2 += v.z; a3 += v.w;
    } else {
      float2 v = *(const float2*)xs;
      a0 += v.x; a1 += v.y;
    }
  }
  float* ag = agg + (size_t)n * DIN + c * VEC;
  if (VEC == 4) {
    *(float4*)ag = make_float4(a0, a1, a2, a3);
  } else {
    *(float2*)ag = make_float2(a0, a1);
  }
}

// ---------------------------------------------------------------------------
// Dense (layers 1,2): thread per (node, out-feature), weights in LDS.
// ---------------------------------------------------------------------------
template<int DIN>
__global__ __launch_bounds__(256) void dense_relu_kernel(
    const float* __restrict__ agg, const float* __restrict__ xin,
    const float* __restrict__ Wrel, const float* __restrict__ b,
    const float* __restrict__ Wroot, float* __restrict__ out, int n_nodes) {
  __shared__ float sWrel[DIN * HH];
  __shared__ float sWroot[DIN * HH];
  __shared__ float sb[HH];
  for (int i = threadIdx.x; i < DIN * HH; i += 256) {
    sWrel[i] = Wrel[i];
    sWroot[i] = Wroot[i];
  }
  if (threadIdx.x < HH) sb[threadIdx.x] = b[threadIdx.x];
  __syncthreads();
  int idx = blockIdx.x * 256 + threadIdx.x;
  if (idx >= n_nodes * HH) return;
  int n = idx / HH;
  int j = idx - n * HH;
  const float* ar = agg + (size_t)n * DIN;
  const float* xr = xin + (size_t)n * DIN;
  float acc = sb[j];
#pragma unroll
  for (int f = 0; f < DIN; f++) {
    acc += ar[f] * sWrel[f * HH + j];
    acc += xr[f] * sWroot[f * HH + j];
  }
  out[idx] = fmaxf(acc, 0.0f);
}

// ---------------------------------------------------------------------------
// Dense layer 3 fused with pooling. Thread per node; per-block per-graph
// partials in LDS (batch sorted -> few graphs per block), then few global
// atomics. Post-ReLU >= 0 so int atomicMax on float bits is order-correct.
// ---------------------------------------------------------------------------
#define GMAX 8
__global__ __launch_bounds__(256) void dense_pool_kernel(
    const float* __restrict__ agg, const float* __restrict__ xin,
    const float* __restrict__ Wrel, const float* __restrict__ bb,
    const float* __restrict__ Wroot, const int* __restrict__ batch,
    float* __restrict__ sump, int* __restrict__ maxp, float* __restrict__ cnt,
    int n_nodes) {
  __shared__ float sWrel[HH * HH];
  __shared__ float sWroot[HH * HH];
  __shared__ float sb[HH];
  __shared__ float gsum[GMAX * HH];
  __shared__ int gmax[GMAX * HH];
  __shared__ int gcnt[GMAX];
  __shared__ int g0s;
  int t = threadIdx.x;
  for (int i = t; i < HH * HH; i += 256) {
    sWrel[i] = Wrel[i];
    sWroot[i] = Wroot[i];
  }
  if (t < HH) sb[t] = bb[t];
  for (int i = t; i < GMAX * HH; i += 256) {
    gsum[i] = 0.0f;
    gmax[i] = 0;
  }
  if (t < GMAX) gcnt[t] = 0;
  if (t == 0) g0s = batch[blockIdx.x * 256];
  __syncthreads();

  int n = blockIdx.x * 256 + t;
  if (n < n_nodes) {
    float ar[HH], xr[HH];
    const float* ap = agg + (size_t)n * HH;
    const float* xp = xin + (size_t)n * HH;
#pragma unroll
    for (int c = 0; c < 5; c++) {
      float4 v = *(const float4*)(ap + 4 * c);
      ar[4 * c + 0] = v.x; ar[4 * c + 1] = v.y;
      ar[4 * c + 2] = v.z; ar[4 * c + 3] = v.w;
      float4 w = *(const float4*)(xp + 4 * c);
      xr[4 * c + 0] = w.x; xr[4 * c + 1] = w.y;
      xr[4 * c + 2] = w.z; xr[4 * c + 3] = w.w;
    }
    float o[HH];
#pragma unroll
    for (int j = 0; j < HH; j++) o[j] = sb[j];
#pragma unroll
    for (int f = 0; f < HH; f++) {
      float a = ar[f], xv = xr[f];
#pragma unroll
      for (int j = 0; j < HH; j++)
        o[j] += a * sWrel[f * HH + j] + xv * sWroot[f * HH + j];
    }
#pragma unroll
    for (int j = 0; j < HH; j++) o[j] = fmaxf(o[j], 0.0f);

    int g = batch[n];
    int gl = g - g0s;
    if (gl >= 0 && gl < GMAX) {
      atomicAdd(&gcnt[gl], 1);
#pragma unroll
      for (int j = 0; j < HH; j++) {
        atomicAdd(&gsum[gl * HH + j], o[j]);
        atomicMax(&gmax[gl * HH + j], __float_as_int(o[j]));
      }
    } else {  // pathological fallback
      atomicAdd(&cnt[g], 1.0f);
#pragma unroll
      for (int j = 0; j < HH; j++) {
        atomicAdd(&sump[g * HH + j], o[j]);
        atomicMax(&maxp[g * HH + j], __float_as_int(o[j]));
      }
    }
  }
  __syncthreads();

  for (int i = t; i < GMAX * HH; i += 256) {
    int gl = i / HH;
    int g = g0s + gl;
    if (g < GG) {
      float sv = gsum[i];
      if (sv != 0.0f) atomicAdd(&sump[g * HH + (i - gl * HH)], sv);
      int mv = gmax[i];
      if (mv != 0) atomicMax(&maxp[g * HH + (i - gl * HH)], mv);
    }
  }
  if (t < GMAX) {
    int c = gcnt[t];
    int g = g0s + t;
    if (c && g < GG) atomicAdd(&cnt[g], (float)c);
  }
}

__global__ __launch_bounds__(256) void readout_kernel(
    const float* __restrict__ sump, const int* __restrict__ maxp,
    const float* __restrict__ cnt, const float* __restrict__ Wlin,
    const float* __restrict__ blin, float* __restrict__ out) {
  int idx = blockIdx.x * 256 + threadIdx.x;
  if (idx >= GG * LL) return;
  int g = idx / LL;
  int l = idx - g * LL;
  float c = cnt[g];
  float inv = 1.0f / fmaxf(c, 1.0f);
  float acc = blin[l];
#pragma unroll
  for (int j = 0; j < HH; j++) {
    float mx = __int_as_float(maxp[g * HH + j]);
    float mean = sump[g * HH + j] * inv;
    acc += mx * Wlin[j * LL + l];
    acc += mean * Wlin[(HH + j) * LL + l];
  }
  out[idx] = acc;
}

extern "C" void kernel_launch(void* const* d_in, const int* in_sizes, int n_in,
                              void* d_out, int out_size, void* d_ws,
                              size_t ws_size, hipStream_t stream) {
  const float* x = (const float*)d_in[0];
  const int* edge_index = (const int*)d_in[1];
  const int* batch = (const int*)d_in[2];
  const float* W_rel1 = (const float*)d_in[3];
  const float* b1 = (const float*)d_in[4];
  const float* W_root1 = (const float*)d_in[5];
  const float* W_rel2 = (const float*)d_in[6];
  const float* b2 = (const float*)d_in[7];
  const float* W_root2 = (const float*)d_in[8];
  const float* W_rel3 = (const float*)d_in[9];
  const float* b3 = (const float*)d_in[10];
  const float* W_root3 = (const float*)d_in[11];
  const float* W_lin = (const float*)d_in[12];
  const float* b_lin = (const float*)d_in[13];
  float* out = (float*)d_out;

  const int E = in_sizes[1] / 2;
  const int n_nodes = in_sizes[0] / FF;  // == NN
  const int* src = edge_index;
  const int* dst = edge_index + E;

  // Workspace layout. pay (E u32) is dead after bucket_csr_kernel; agg
  // aliases it (NN*HH*4 = 8MB <= E*4 = 12.8MB).
  unsigned int* pay = (unsigned int*)d_ws;       // E u32  | aliased: agg
  int* srt = (int*)(pay + E);                    // E
  int* rofs = srt + E;                           // NN
  int* rend = rofs + NN;                         // NN
  int* bcnt = rend + NN;                         // NB
  int* gofs = bcnt + NB;                         // NB+1
  int* cursor = gofs + NB + 1;                   // NB
  float* sump = (float*)(cursor + NB);           // GG*HH
  int* maxp = (int*)(sump + GG * HH);            // GG*HH
  float* cnt = (float*)(maxp + GG * HH);         // GG
  float* bufA = cnt + GG;                        // NN*HH
  float* bufB = bufA + (size_t)NN * HH;          // NN*HH
  float* agg = (float*)pay;                      // NN*HH (after CSR build)
  // total ~= 12.8 + 12.8 + 0.8 + ~0.1 + 8 + 8 MB ~= 42.5 MB

  const int edge_tiles = (E + TILE - 1) / TILE;
  const int gath_blocks = (n_nodes * 5 + 255) / 256;
  const int node_blocks = (n_nodes + 255) / 256;
  const int nodeF_blocks = (n_nodes * HH + 255) / 256;

  // ---- CSR build via bucketed multisplit ----
  hipMemsetAsync(bcnt, 0, NB * sizeof(int), stream);
  hipMemsetAsync(sump, 0, (size_t)GG * HH * sizeof(float), stream);
  hipMemsetAsync(maxp, 0, (size_t)GG * HH * sizeof(int), stream);
  hipMemsetAsync(cnt, 0, (size_t)GG * sizeof(float), stream);
  bucket_count_kernel<<<edge_tiles, 256, 0, stream>>>(dst, bcnt, E);
  bucket_scan_kernel<<<1, 256, 0, stream>>>(bcnt, gofs, cursor);
  multisplit_kernel<<<edge_tiles, 256, 0, stream>>>(src, dst, cursor, pay, E);
  bucket_csr_kernel<<<NB, 256, 0, stream>>>(pay, gofs, srt, rofs, rend);

  // ---- Layer 1: F(10) -> H(20) ----
  gather_kernel<FF, 2><<<gath_blocks, 256, 0, stream>>>(
      x, rofs, rend, srt, agg, n_nodes);
  dense_relu_kernel<FF><<<nodeF_blocks, 256, 0, stream>>>(
      agg, x, W_rel1, b1, W_root1, bufA, n_nodes);

  // ---- Layer 2: H -> H ----
  gather_kernel<HH, 4><<<gath_blocks, 256, 0, stream>>>(
      bufA, rofs, rend, srt, agg, n_nodes);
  dense_relu_kernel<HH><<<nodeF_blocks, 256, 0, stream>>>(
      agg, bufA, W_rel2, b2, W_root2, bufB, n_nodes);

  // ---- Layer 3: H -> H, fused with pooling ----
  gather_kernel<HH, 4><<<gath_blocks, 256, 0, stream>>>(
      bufB, rofs, rend, srt, agg, n_nodes);
  dense_pool_kernel<<<node_blocks, 256, 0, stream>>>(
      agg, bufB, W_rel3, b3, W_root3, batch, sump, maxp, cnt, n_nodes);

  // ---- Readout ----
  readout_kernel<<<(GG * LL + 255) / 256, 256, 0, stream>>>(
      sump, maxp, cnt, W_lin, b_lin, out);
}

// Round 4
// 367.416 us; speedup vs baseline: 9.3596x; 1.3459x over previous
//
#include <hip/hip_runtime.h>
#include <hip/hip_bf16.h>

#define NN 100000   // nodes
#define FF 10       // input features
#define HH 20       // hidden dim
#define GG 512      // graphs
#define LL 2        // labels

#define NB 400      // dst buckets
#define BNODES 250  // nodes per bucket (NN / NB)
#define TILE 4096   // edges per block in multisplit
#define SRC_BITS 17
#define SRC_MASK 0x1FFFFu

// bf16 helpers (storage-only; all math in f32)
__device__ inline unsigned short f2bf(float f) {
  unsigned u = __float_as_uint(f);
  unsigned r = u + 0x7FFFu + ((u >> 16) & 1u);
  return (unsigned short)(r >> 16);
}
__device__ inline float bflo(unsigned u) { return __uint_as_float(u << 16); }
__device__ inline float bfhi(unsigned u) { return __uint_as_float(u & 0xFFFF0000u); }

// ---------------------------------------------------------------------------
// Cast input features f32 -> bf16
// ---------------------------------------------------------------------------
__global__ __launch_bounds__(256) void cast_bf16_kernel(
    const float* __restrict__ x, unsigned short* __restrict__ xb, int n) {
  int i = blockIdx.x * 256 + threadIdx.x;
  if (i < n) xb[i] = f2bf(x[i]);
}

// ---------------------------------------------------------------------------
// K0: per-bucket edge counts (LDS histogram, then merge).
// ---------------------------------------------------------------------------
__global__ __launch_bounds__(256) void bucket_count_kernel(
    const int* __restrict__ dst, int* __restrict__ bcnt, int E) {
  __shared__ int lh[NB];
  for (int i = threadIdx.x; i < NB; i += 256) lh[i] = 0;
  __syncthreads();
  int base = blockIdx.x * TILE;
  for (int i = threadIdx.x; i < TILE; i += 256) {
    int e = base + i;
    if (e < E) atomicAdd(&lh[dst[e] / BNODES], 1);
  }
  __syncthreads();
  for (int i = threadIdx.x; i < NB; i += 256) {
    int c = lh[i];
    if (c) atomicAdd(&bcnt[i], c);
  }
}

// ---------------------------------------------------------------------------
// K1: scan bucket counts -> gofs[NB+1], init cursor. 256 thr, 2 elems each.
// ---------------------------------------------------------------------------
__global__ __launch_bounds__(256) void bucket_scan_kernel(
    const int* __restrict__ bcnt, int* __restrict__ gofs,
    int* __restrict__ cursor) {
  __shared__ int ss[512];
  int t = threadIdx.x;
  int own0 = (t < NB) ? bcnt[t] : 0;
  int own1 = (t + 256 < NB) ? bcnt[t + 256] : 0;
  ss[t] = own0;
  ss[t + 256] = own1;
  __syncthreads();
  for (int off = 1; off < 512; off <<= 1) {
    int a0 = (t >= off) ? ss[t - off] : 0;
    int a1 = (t + 256 >= off) ? ss[t + 256 - off] : 0;
    __syncthreads();
    ss[t] += a0;
    ss[t + 256] += a1;
    __syncthreads();
  }
  if (t < NB) {
    int ex = ss[t] - own0;
    gofs[t] = ex;
    cursor[t] = ex;
  }
  int i1 = t + 256;
  if (i1 < NB) {
    int ex = ss[i1] - own1;
    gofs[i1] = ex;
    cursor[i1] = ex;
  }
  if (t == 0) gofs[NB] = ss[NB - 1];
}

// ---------------------------------------------------------------------------
// K2: multisplit. Reorder a TILE of edges by bucket in LDS, write bucket runs
// contiguously. Payload pack: (local_dst << 17) | src.
// ---------------------------------------------------------------------------
__global__ __launch_bounds__(256) void multisplit_kernel(
    const int* __restrict__ src, const int* __restrict__ dst,
    int* __restrict__ cursor, unsigned int* __restrict__ pay, int E) {
  __shared__ unsigned int spay[TILE];
  __shared__ unsigned int sbkr[TILE];    // (bucket<<16) | rank
  __shared__ unsigned int sord[TILE];    // bucket-sorted payloads
  __shared__ unsigned short sdbk[TILE];  // bucket of each sorted slot
  __shared__ int lhist[NB];
  __shared__ int lofs[NB];
  __shared__ int gbase[NB];
  __shared__ int sscan[512];

  int t = threadIdx.x;
  for (int i = t; i < NB; i += 256) lhist[i] = 0;
  __syncthreads();

  int base = blockIdx.x * TILE;
  int count = E - base;
  if (count > TILE) count = TILE;

  for (int i = t; i < TILE; i += 256) {
    int e = base + i;
    if (e < E) {
      int d = dst[e];
      int s = src[e];
      int bk = d / BNODES;
      int ld = d - bk * BNODES;
      spay[i] = ((unsigned)ld << SRC_BITS) | (unsigned)s;
      int r = atomicAdd(&lhist[bk], 1);
      sbkr[i] = ((unsigned)bk << 16) | (unsigned)r;
    } else {
      sbkr[i] = 0xFFFFFFFFu;
    }
  }
  __syncthreads();

  // exclusive scan of lhist (NB <= 512), 2 elems/thread
  int own0 = (t < NB) ? lhist[t] : 0;
  int own1 = (t + 256 < NB) ? lhist[t + 256] : 0;
  sscan[t] = own0;
  sscan[t + 256] = own1;
  __syncthreads();
  for (int off = 1; off < 512; off <<= 1) {
    int a0 = (t >= off) ? sscan[t - off] : 0;
    int a1 = (t + 256 >= off) ? sscan[t + 256 - off] : 0;
    __syncthreads();
    sscan[t] += a0;
    sscan[t + 256] += a1;
    __syncthreads();
  }
  if (t < NB) {
    lofs[t] = sscan[t] - own0;
    gbase[t] = own0 ? atomicAdd(&cursor[t], own0) : 0;
  }
  if (t + 256 < NB) {
    lofs[t + 256] = sscan[t + 256] - own1;
    gbase[t + 256] = own1 ? atomicAdd(&cursor[t + 256], own1) : 0;
  }
  __syncthreads();

  // scatter into bucket-sorted LDS order
  for (int i = t; i < TILE; i += 256) {
    unsigned int br = sbkr[i];
    if (br != 0xFFFFFFFFu) {
      int bk = br >> 16;
      int r = br & 0xFFFF;
      int slot = lofs[bk] + r;
      sord[slot] = spay[i];
      sdbk[slot] = (unsigned short)bk;
    }
  }
  __syncthreads();

  // coalesced run writes
  for (int i = t; i < count; i += 256) {
    int bk = sdbk[i];
    pay[gbase[bk] + (i - lofs[bk])] = sord[i];
  }
}

// ---------------------------------------------------------------------------
// K3: per-bucket CSR finalize. One block owns a 250-node bucket.
// ---------------------------------------------------------------------------
__global__ __launch_bounds__(256) void bucket_csr_kernel(
    const unsigned int* __restrict__ pay, const int* __restrict__ gofs,
    int* __restrict__ srt, int* __restrict__ rofs, int* __restrict__ rend) {
  __shared__ int lhist[BNODES];
  __shared__ int lofs[BNODES];
  __shared__ int lcur[BNODES];
  __shared__ int ss[256];
  int b = blockIdx.x;
  int t = threadIdx.x;
  int k0 = gofs[b], k1 = gofs[b + 1];

  if (t < BNODES) lhist[t] = 0;
  __syncthreads();
  for (int k = k0 + t; k < k1; k += 256)
    atomicAdd(&lhist[pay[k] >> SRC_BITS], 1);
  __syncthreads();

  int own = (t < BNODES) ? lhist[t] : 0;
  ss[t] = own;
  __syncthreads();
  for (int off = 1; off < 256; off <<= 1) {
    int a0 = (t >= off) ? ss[t - off] : 0;
    __syncthreads();
    ss[t] += a0;
    __syncthreads();
  }
  if (t < BNODES) {
    int ex = ss[t] - own;
    lofs[t] = ex;
    lcur[t] = 0;
    rofs[b * BNODES + t] = k0 + ex;
    rend[b * BNODES + t] = k0 + ex + own;
  }
  __syncthreads();

  for (int k = k0 + t; k < k1; k += 256) {
    unsigned int p = pay[k];
    int ld = p >> SRC_BITS;
    int s = (int)(p & SRC_MASK);
    int r = atomicAdd(&lcur[ld], 1);
    srt[k0 + lofs[ld] + r] = s;
  }
}

// ---------------------------------------------------------------------------
// Gather (bf16 rows): thread per (node, chunk); 5 chunks cover a row.
// DIN=20: chunk = 4 bf16 (8B uint2). DIN=10: chunk = 2 bf16 (4B uint).
// Accumulation in f32. Manual 4x unroll for outstanding loads.
// ---------------------------------------------------------------------------
template<int DIN>
__global__ __launch_bounds__(256) void gather_bf16_kernel(
    const unsigned short* __restrict__ xin, const int* __restrict__ rofs,
    const int* __restrict__ rend, const int* __restrict__ srt,
    float* __restrict__ agg, int n_nodes) {
  int id = blockIdx.x * 256 + threadIdx.x;
  if (id >= n_nodes * 5) return;
  int n = id / 5;
  int c = id - n * 5;
  int k0 = rofs[n], k1 = rend[n];
  float a0 = 0, a1 = 0, a2 = 0, a3 = 0;
  if (DIN == 20) {
    const unsigned short* xb = xin + c * 4;
    int k = k0;
    for (; k + 3 < k1; k += 4) {
      int s0 = srt[k], s1 = srt[k + 1], s2 = srt[k + 2], s3 = srt[k + 3];
      uint2 u0 = *(const uint2*)(xb + (size_t)s0 * 20);
      uint2 u1 = *(const uint2*)(xb + (size_t)s1 * 20);
      uint2 u2 = *(const uint2*)(xb + (size_t)s2 * 20);
      uint2 u3 = *(const uint2*)(xb + (size_t)s3 * 20);
      a0 += bflo(u0.x) + bflo(u1.x) + bflo(u2.x) + bflo(u3.x);
      a1 += bfhi(u0.x) + bfhi(u1.x) + bfhi(u2.x) + bfhi(u3.x);
      a2 += bflo(u0.y) + bflo(u1.y) + bflo(u2.y) + bflo(u3.y);
      a3 += bfhi(u0.y) + bfhi(u1.y) + bfhi(u2.y) + bfhi(u3.y);
    }
    for (; k < k1; k++) {
      int s = srt[k];
      uint2 u = *(const uint2*)(xb + (size_t)s * 20);
      a0 += bflo(u.x);
      a1 += bfhi(u.x);
      a2 += bflo(u.y);
      a3 += bfhi(u.y);
    }
    float* ag = agg + (size_t)n * 20 + c * 4;
    *(float4*)ag = make_float4(a0, a1, a2, a3);
  } else {
    const unsigned short* xb = xin + c * 2;
    int k = k0;
    for (; k + 3 < k1; k += 4) {
      int s0 = srt[k], s1 = srt[k + 1], s2 = srt[k + 2], s3 = srt[k + 3];
      unsigned u0 = *(const unsigned*)(xb + (size_t)s0 * 10);
      unsigned u1 = *(const unsigned*)(xb + (size_t)s1 * 10);
      unsigned u2 = *(const unsigned*)(xb + (size_t)s2 * 10);
      unsigned u3 = *(const unsigned*)(xb + (size_t)s3 * 10);
      a0 += bflo(u0) + bflo(u1) + bflo(u2) + bflo(u3);
      a1 += bfhi(u0) + bfhi(u1) + bfhi(u2) + bfhi(u3);
    }
    for (; k < k1; k++) {
      int s = srt[k];
      unsigned u = *(const unsigned*)(xb + (size_t)s * 10);
      a0 += bflo(u);
      a1 += bfhi(u);
    }
    float* ag = agg + (size_t)n * 10 + c * 2;
    *(float2*)ag = make_float2(a0, a1);
  }
}

// ---------------------------------------------------------------------------
// Dense (layers 1,2): thread per (node, out-feature), weights in LDS.
// agg f32, root input bf16, output bf16.
// ---------------------------------------------------------------------------
template<int DIN>
__global__ __launch_bounds__(256) void dense_relu_kernel(
    const float* __restrict__ agg, const unsigned short* __restrict__ xin,
    const float* __restrict__ Wrel, const float* __restrict__ b,
    const float* __restrict__ Wroot, unsigned short* __restrict__ out,
    int n_nodes) {
  __shared__ float sWrel[DIN * HH];
  __shared__ float sWroot[DIN * HH];
  __shared__ float sb[HH];
  for (int i = threadIdx.x; i < DIN * HH; i += 256) {
    sWrel[i] = Wrel[i];
    sWroot[i] = Wroot[i];
  }
  if (threadIdx.x < HH) sb[threadIdx.x] = b[threadIdx.x];
  __syncthreads();
  int idx = blockIdx.x * 256 + threadIdx.x;
  if (idx >= n_nodes * HH) return;
  int n = idx / HH;
  int j = idx - n * HH;
  const float* ar = agg + (size_t)n * DIN;
  const unsigned short* xr = xin + (size_t)n * DIN;
  float acc = sb[j];
#pragma unroll
  for (int f = 0; f < DIN; f++) {
    acc += ar[f] * sWrel[f * HH + j];
    acc += bflo((unsigned)xr[f]) * sWroot[f * HH + j];
  }
  out[idx] = f2bf(fmaxf(acc, 0.0f));
}

// ---------------------------------------------------------------------------
// Dense layer 3 fused with pooling. Thread per node; per-block per-graph
// partials in LDS, few global atomics. Post-ReLU >= 0 so int atomicMax on
// float bits is order-correct; memset-0 init gives where(cnt>0,max,0).
// ---------------------------------------------------------------------------
#define GMAX 8
__global__ __launch_bounds__(256) void dense_pool_kernel(
    const float* __restrict__ agg, const unsigned short* __restrict__ xin,
    const float* __restrict__ Wrel, const float* __restrict__ bb,
    const float* __restrict__ Wroot, const int* __restrict__ batch,
    float* __restrict__ sump, int* __restrict__ maxp, float* __restrict__ cnt,
    int n_nodes) {
  __shared__ float sWrel[HH * HH];
  __shared__ float sWroot[HH * HH];
  __shared__ float sb[HH];
  __shared__ float gsum[GMAX * HH];
  __shared__ int gmax[GMAX * HH];
  __shared__ int gcnt[GMAX];
  __shared__ int g0s;
  int t = threadIdx.x;
  for (int i = t; i < HH * HH; i += 256) {
    sWrel[i] = Wrel[i];
    sWroot[i] = Wroot[i];
  }
  if (t < HH) sb[t] = bb[t];
  for (int i = t; i < GMAX * HH; i += 256) {
    gsum[i] = 0.0f;
    gmax[i] = 0;
  }
  if (t < GMAX) gcnt[t] = 0;
  if (t == 0) g0s = batch[blockIdx.x * 256];
  __syncthreads();

  int n = blockIdx.x * 256 + t;
  if (n < n_nodes) {
    float ar[HH], xr[HH];
    const float* ap = agg + (size_t)n * HH;
    const uint2* xp = (const uint2*)(xin + (size_t)n * HH);
#pragma unroll
    for (int c = 0; c < 5; c++) {
      float4 v = *(const float4*)(ap + 4 * c);
      ar[4 * c + 0] = v.x; ar[4 * c + 1] = v.y;
      ar[4 * c + 2] = v.z; ar[4 * c + 3] = v.w;
      uint2 u = xp[c];
      xr[4 * c + 0] = bflo(u.x); xr[4 * c + 1] = bfhi(u.x);
      xr[4 * c + 2] = bflo(u.y); xr[4 * c + 3] = bfhi(u.y);
    }
    float o[HH];
#pragma unroll
    for (int j = 0; j < HH; j++) o[j] = sb[j];
#pragma unroll
    for (int f = 0; f < HH; f++) {
      float a = ar[f], xv = xr[f];
#pragma unroll
      for (int j = 0; j < HH; j++)
        o[j] += a * sWrel[f * HH + j] + xv * sWroot[f * HH + j];
    }
#pragma unroll
    for (int j = 0; j < HH; j++) o[j] = fmaxf(o[j], 0.0f);

    int g = batch[n];
    int gl = g - g0s;
    if (gl >= 0 && gl < GMAX) {
      atomicAdd(&gcnt[gl], 1);
#pragma unroll
      for (int j = 0; j < HH; j++) {
        atomicAdd(&gsum[gl * HH + j], o[j]);
        atomicMax(&gmax[gl * HH + j], __float_as_int(o[j]));
      }
    } else {  // pathological fallback
      atomicAdd(&cnt[g], 1.0f);
#pragma unroll
      for (int j = 0; j < HH; j++) {
        atomicAdd(&sump[g * HH + j], o[j]);
        atomicMax(&maxp[g * HH + j], __float_as_int(o[j]));
      }
    }
  }
  __syncthreads();

  for (int i = t; i < GMAX * HH; i += 256) {
    int gl = i / HH;
    int g = g0s + gl;
    if (g < GG) {
      float sv = gsum[i];
      if (sv != 0.0f) atomicAdd(&sump[g * HH + (i - gl * HH)], sv);
      int mv = gmax[i];
      if (mv != 0) atomicMax(&maxp[g * HH + (i - gl * HH)], mv);
    }
  }
  if (t < GMAX) {
    int c = gcnt[t];
    int g = g0s + t;
    if (c && g < GG) atomicAdd(&cnt[g], (float)c);
  }
}

__global__ __launch_bounds__(256) void readout_kernel(
    const float* __restrict__ sump, const int* __restrict__ maxp,
    const float* __restrict__ cnt, const float* __restrict__ Wlin,
    const float* __restrict__ blin, float* __restrict__ out) {
  int idx = blockIdx.x * 256 + threadIdx.x;
  if (idx >= GG * LL) return;
  int g = idx / LL;
  int l = idx - g * LL;
  float c = cnt[g];
  float inv = 1.0f / fmaxf(c, 1.0f);
  float acc = blin[l];
#pragma unroll
  for (int j = 0; j < HH; j++) {
    float mx = __int_as_float(maxp[g * HH + j]);
    float mean = sump[g * HH + j] * inv;
    acc += mx * Wlin[j * LL + l];
    acc += mean * Wlin[(HH + j) * LL + l];
  }
  out[idx] = acc;
}

extern "C" void kernel_launch(void* const* d_in, const int* in_sizes, int n_in,
                              void* d_out, int out_size, void* d_ws,
                              size_t ws_size, hipStream_t stream) {
  const float* x = (const float*)d_in[0];
  const int* edge_index = (const int*)d_in[1];
  const int* batch = (const int*)d_in[2];
  const float* W_rel1 = (const float*)d_in[3];
  const float* b1 = (const float*)d_in[4];
  const float* W_root1 = (const float*)d_in[5];
  const float* W_rel2 = (const float*)d_in[6];
  const float* b2 = (const float*)d_in[7];
  const float* W_root2 = (const float*)d_in[8];
  const float* W_rel3 = (const float*)d_in[9];
  const float* b3 = (const float*)d_in[10];
  const float* W_root3 = (const float*)d_in[11];
  const float* W_lin = (const float*)d_in[12];
  const float* b_lin = (const float*)d_in[13];
  float* out = (float*)d_out;

  const int E = in_sizes[1] / 2;
  const int n_nodes = in_sizes[0] / FF;  // == NN
  const int* src = edge_index;
  const int* dst = edge_index + E;

  // Workspace layout. pay (E u32) is dead after bucket_csr; agg aliases it
  // (NN*HH*4 = 8MB <= E*4 = 12.8MB).
  unsigned int* pay = (unsigned int*)d_ws;       // E u32 | aliased: agg
  int* srt = (int*)(pay + E);                    // E
  int* rofs = srt + E;                           // NN
  int* rend = rofs + NN;                         // NN
  int* bcnt = rend + NN;                         // NB
  int* gofs = bcnt + NB;                         // NB+1
  int* cursor = gofs + NB + 1;                   // NB
  float* sump = (float*)(cursor + NB);           // GG*HH
  int* maxp = (int*)(sump + GG * HH);            // GG*HH
  float* cnt = (float*)(maxp + GG * HH);         // GG (+1 pad for 8B align)
  unsigned short* xb = (unsigned short*)(cnt + GG + 1);  // NN*FF bf16
  unsigned short* h1 = xb + (size_t)NN * FF;     // NN*HH bf16
  unsigned short* h2 = h1 + (size_t)NN * HH;     // NN*HH bf16
  float* agg = (float*)pay;                      // NN*HH f32 (after CSR build)

  const int edge_tiles = (E + TILE - 1) / TILE;
  const int gath_blocks = (n_nodes * 5 + 255) / 256;
  const int node_blocks = (n_nodes + 255) / 256;
  const int nodeF_blocks = (n_nodes * HH + 255) / 256;

  // ---- Pre-cast x to bf16; zero pool accumulators ----
  hipMemsetAsync(bcnt, 0, NB * sizeof(int), stream);
  hipMemsetAsync(sump, 0, (size_t)GG * HH * sizeof(float), stream);
  hipMemsetAsync(maxp, 0, (size_t)GG * HH * sizeof(int), stream);
  hipMemsetAsync(cnt, 0, (size_t)GG * sizeof(float), stream);
  cast_bf16_kernel<<<(n_nodes * FF + 255) / 256, 256, 0, stream>>>(
      x, xb, n_nodes * FF);

  // ---- CSR build via bucketed multisplit ----
  bucket_count_kernel<<<edge_tiles, 256, 0, stream>>>(dst, bcnt, E);
  bucket_scan_kernel<<<1, 256, 0, stream>>>(bcnt, gofs, cursor);
  multisplit_kernel<<<edge_tiles, 256, 0, stream>>>(src, dst, cursor, pay, E);
  bucket_csr_kernel<<<NB, 256, 0, stream>>>(pay, gofs, srt, rofs, rend);

  // ---- Layer 1: F(10) -> H(20) ----
  gather_bf16_kernel<FF><<<gath_blocks, 256, 0, stream>>>(
      xb, rofs, rend, srt, agg, n_nodes);
  dense_relu_kernel<FF><<<nodeF_blocks, 256, 0, stream>>>(
      agg, xb, W_rel1, b1, W_root1, h1, n_nodes);

  // ---- Layer 2: H -> H ----
  gather_bf16_kernel<HH><<<gath_blocks, 256, 0, stream>>>(
      h1, rofs, rend, srt, agg, n_nodes);
  dense_relu_kernel<HH><<<nodeF_blocks, 256, 0, stream>>>(
      agg, h1, W_rel2, b2, W_root2, h2, n_nodes);

  // ---- Layer 3: H -> H, fused with pooling ----
  gather_bf16_kernel<HH><<<gath_blocks, 256, 0, stream>>>(
      h2, rofs, rend, srt, agg, n_nodes);
  dense_pool_kernel<<<node_blocks, 256, 0, stream>>>(
      agg, h2, W_rel3, b3, W_root3, batch, sump, maxp, cnt, n_nodes);

  // ---- Readout ----
  readout_kernel<<<(GG * LL + 255) / 256, 256, 0, stream>>>(
      sump, maxp, cnt, W_lin, b_lin, out);
}